// Round 12
// baseline (247.580 us; speedup 1.0000x reference)
//
#include <hip/hip_runtime.h>
#include <hip/hip_bf16.h>

typedef unsigned long long u64;
typedef unsigned int u32;

#define LOG2E 1.44269504088896340736f
#define LN2   0.69314718055994530942f

// ---------- fast math ----------
__device__ __forceinline__ float fexp2(float x) { return __builtin_amdgcn_exp2f(x); }
__device__ __forceinline__ float flog2(float x) { return __builtin_amdgcn_logf(x); }
__device__ __forceinline__ float frcp(float x)  { return __builtin_amdgcn_rcpf(x); }
__device__ __forceinline__ float keyval(u64 k) { return __uint_as_float((u32)(k >> 32)); }

__device__ __forceinline__ float iou_xyxy(float ax1, float ay1, float ax2, float ay2,
                                          float bx1, float by1, float bx2, float by2) {
    float ltx = fmaxf(ax1, bx1), lty = fmaxf(ay1, by1);
    float rbx = fminf(ax2, bx2), rby = fminf(ay2, by2);
    float w = fmaxf(rbx - ltx, 0.0f), h = fmaxf(rby - lty, 0.0f);
    float inter = w * h;
    float areaA = (ax2 - ax1) * (ay2 - ay1);
    float areaB = (bx2 - bx1) * (by2 - by1);
    return inter / (areaA + areaB - inter);
}

// ---------- K1: fused main pass (reg path + gfocal stream + pred path) ----------
__global__ __launch_bounds__(256) void k_main(
        const float* __restrict__ loc, const float* __restrict__ conf,
        const float* __restrict__ priors, const float* __restrict__ truths,
        const int* __restrict__ labels,
        u64* __restrict__ basekeyR, u64* __restrict__ ovkey,
        u64* __restrict__ basekeyP, u64* __restrict__ predkey,
        double* __restrict__ partC, u32* __restrict__ pcnt, int P) {
    int n = blockIdx.y, p0 = blockIdx.x * 64, tid = threadIdx.x;
    int r = tid >> 2, sub = tid & 3, p = p0 + r;
    bool act = p < P;

    if (blockIdx.x == 0 && tid == 0) pcnt[n] = 0u;   // benign (pre-tsel)

    // issue ALL global loads first (in flight across LDS setup barriers)
    float4 L0, L1, L2, L3, L4, prv, lc;
    L0 = L1 = L2 = L3 = L4 = prv = lc = make_float4(0.f, 0.f, 0.f, 0.f);
    if (act) {
        const float* rowp = conf + ((size_t)n * P + p) * 80 + sub * 4;
        L0 = *(const float4*)(rowp);
        L1 = *(const float4*)(rowp + 16);
        L2 = *(const float4*)(rowp + 32);
        L3 = *(const float4*)(rowp + 48);
        L4 = *(const float4*)(rowp + 64);
        prv = *(const float4*)(priors + (size_t)p * 4);
        lc  = *(const float4*)(loc + ((size_t)n * P + p) * 4);
    }

    __shared__ float strt[64];
    __shared__ int   lab[16];
    __shared__ u32   smask[80];
    __shared__ float sglab[64][17];
    if (tid < 64) strt[tid] = truths[n * 64 + tid];
    if (tid < 80) smask[tid] = 0u;
    __syncthreads();
    if (tid < 16) {
        int lb = labels[n * 16 + tid];
        lab[tid] = lb;
        atomicOr(&smask[lb], 1u << tid);
    }
    __syncthreads();

    u32 mybits = 0;
    #pragma unroll
    for (int k = 0; k < 5; k++) {
        #pragma unroll
        for (int j = 0; j < 4; j++) {
            if (smask[k * 16 + sub * 4 + j]) mybits |= 1u << (k * 4 + j);
        }
    }

    // ---- reg path: decoded box IoUs -> basekeyR + ovkey
    {
        float vv[4] = {0, 0, 0, 0};
        u64 mykey = 0;
        if (act) {
            float cx = prv.x + lc.x * 0.1f * prv.z;
            float cy = prv.y + lc.y * 0.1f * prv.w;
            float w  = prv.z * fexp2(lc.z * 0.2f * LOG2E);
            float h  = prv.w * fexp2(lc.w * 0.2f * LOG2E);
            float bx1 = cx - w * 0.5f, by1 = cy - h * 0.5f;
            float bx2 = cx + w * 0.5f, by2 = cy + h * 0.5f;
            #pragma unroll
            for (int jj = 0; jj < 4; jj++) {
                int o = sub * 4 + jj;
                float v = iou_xyxy(strt[o * 4], strt[o * 4 + 1], strt[o * 4 + 2],
                                   strt[o * 4 + 3], bx1, by1, bx2, by2);
                vv[jj] = v;
                u64 kk = ((u64)__float_as_uint(v) << 32) | (u32)(~(u32)o);
                if (kk > mykey) mykey = kk;
            }
        }
        { u64 t = __shfl_xor(mykey, 1, 64); if (t > mykey) mykey = t;
          t = __shfl_xor(mykey, 2, 64); if (t > mykey) mykey = t; }
        float m = keyval(mykey);
        u32 bits = 0;
        #pragma unroll
        for (int jj = 0; jj < 4; jj++) {
            if (act && vv[jj] == m) bits |= 1u << (sub * 4 + jj);
        }
        bits |= __shfl_xor(bits, 1, 64);
        bits |= __shfl_xor(bits, 2, 64);
        if (act && sub == 0) {
            size_t idx = (size_t)n * P + p;
            basekeyR[idx] = ((u64)__float_as_uint(m) << 32) | bits;
            ovkey[idx]    = mykey;
        }
    }

    // ---- gfocal stream, t = 0 everywhere (corrections in k_correct)
    float lsum = 0.0f;
    if (act) {
        float lv[20] = {L0.x, L0.y, L0.z, L0.w, L1.x, L1.y, L1.z, L1.w,
                        L2.x, L2.y, L2.z, L2.w, L3.x, L3.y, L3.z, L3.w,
                        L4.x, L4.y, L4.z, L4.w};
        #pragma unroll
        for (int k = 0; k < 5; k++) {
            #pragma unroll
            for (int j = 0; j < 4; j++) {
                float lg = lv[k * 4 + j];
                float e  = fexp2(-fabsf(lg) * LOG2E);
                float ln1pe = flog2(1.0f + e) * LN2;
                float rc = frcp(1.0f + e);
                float sg = (lg >= 0.0f) ? rc : e * rc;
                lsum += sg * sg * (fmaxf(lg, 0.0f) + ln1pe);
                if (mybits & (1u << (k * 4 + j))) {
                    u32 m16 = smask[k * 16 + sub * 4 + j];
                    while (m16) {
                        int o = __ffs(m16) - 1;
                        sglab[r][o] = sg;
                        m16 &= m16 - 1;
                    }
                }
            }
        }
    }
    __syncthreads();

    // ---- pred path: prior-box IoUs + sglab -> basekeyP + predkey
    {
        float pv[4] = {0, 0, 0, 0};
        u64 pkey = 0;
        if (act) {
            float px1 = prv.x - prv.z * 0.5f, py1 = prv.y - prv.w * 0.5f;
            float px2 = prv.x + prv.z * 0.5f, py2 = prv.y + prv.w * 0.5f;
            #pragma unroll
            for (int jj = 0; jj < 4; jj++) {
                int o = sub * 4 + jj;
                float ov = iou_xyxy(strt[o * 4], strt[o * 4 + 1], strt[o * 4 + 2],
                                    strt[o * 4 + 3], px1, py1, px2, py2);
                float pd = 0.0f;
                if (ov > 0.0f) {
                    float pc = sglab[r][o];
                    pd = fexp2((2.0f - pc) * 0.5f * flog2(ov));
                }
                pv[jj] = pd;
                u64 kk = ((u64)__float_as_uint(pd) << 32) | (u32)(~(u32)o);
                if (kk > pkey) pkey = kk;
            }
        }
        { u64 t = __shfl_xor(pkey, 1, 64); if (t > pkey) pkey = t;
          t = __shfl_xor(pkey, 2, 64); if (t > pkey) pkey = t; }
        float pm = keyval(pkey);
        u32 bits = 0;
        #pragma unroll
        for (int jj = 0; jj < 4; jj++) {
            if (act && pv[jj] == pm) bits |= 1u << (sub * 4 + jj);
        }
        bits |= __shfl_xor(bits, 1, 64);
        bits |= __shfl_xor(bits, 2, 64);
        if (act && sub == 0) {
            size_t idx = (size_t)n * P + p;
            basekeyP[idx] = ((u64)__float_as_uint(pm) << 32) | bits;
            predkey[idx]  = pkey;
        }
    }

    // ---- block reduce gfocal partials -> per-block slot (no atomic)
    #pragma unroll
    for (int s = 32; s > 0; s >>= 1) lsum += __shfl_down(lsum, s, 64);
    __shared__ float wsum[4];
    if ((tid & 63) == 0) wsum[tid >> 6] = lsum;
    __syncthreads();
    if (tid == 0) {
        partC[(size_t)blockIdx.y * gridDim.x + blockIdx.x] =
            (double)wsum[0] + (double)wsum[1] + (double)wsum[2] + (double)wsum[3];
    }
}

// ---------- K2: per-(row,z) full top-15 scan + num_pos + boost (fused) ----------
// One block per (row, z). 256 threads scan all P, per-thread sorted-15 in regs,
// per-wave merge (no barriers), wave-0 final merge, then boost/record inline.
__global__ __launch_bounds__(256) void k_tsel(
        const u64* __restrict__ basekeyR, const u64* __restrict__ basekeyP,
        u64* __restrict__ ovkey, u64* __restrict__ predkey,
        u32* __restrict__ plistP, u64* __restrict__ plistE, u32* __restrict__ pcnt,
        int P) {
    int row = blockIdx.x, z = blockIdx.y, tid = threadIdx.x;
    int n = row >> 4, o = row & 15;
    int record = (z == 0);
    const u64* base = (z ? basekeyP : basekeyR) + (size_t)n * P;
    u64* bkey = z ? predkey : ovkey;

    u64 lv[15];
    #pragma unroll
    for (int k = 0; k < 15; k++) lv[k] = 0;

    for (int p = tid; p < P; p += 256) {
        u64 b = base[p];
        if ((u32)(b >> 32) != 0u && ((b >> o) & 1)) {
            u64 key = (b & 0xFFFFFFFF00000000ULL) | (u32)(~(u32)p);
            if (key > lv[14]) {
                #pragma unroll
                for (int k = 14; k >= 0; k--) {
                    bool shift = (k > 0) && (key > lv[k - 1]);
                    if (shift)            lv[k] = lv[k - 1];
                    else if (key > lv[k]) lv[k] = key;
                }
            }
        }
    }

    __shared__ u64 cnd[256 * 15];         // 30 KB
    #pragma unroll
    for (int k = 0; k < 15; k++) cnd[tid * 15 + k] = lv[k];
    __syncthreads();

    // wave-level merge: each wave merges its 64 sorted lists (keys unique)
    int lane = tid & 63, wv = tid >> 6;
    const u64* wbase = cnd + wv * 64 * 15;
    int hp = 0;
    u64 mine = 0;
    for (int j = 0; j < 15; j++) {
        u64 prop = (hp < 15) ? wbase[lane * 15 + hp] : 0ULL;
        u64 m = prop;
        #pragma unroll
        for (int s = 32; s >= 1; s >>= 1) { u64 t = __shfl_xor(m, s, 64); if (t > m) m = t; }
        if (m != 0ULL && prop == m) hp++;
        if (lane == j) mine = m;
    }
    __shared__ u64 wl[4][15];
    if (lane < 15) wl[wv][lane] = mine;
    __syncthreads();

    __shared__ u64 selk[15];
    __shared__ int s_num;
    if (wv == 0) {
        int hq = 0;
        u64 outk = 0;
        for (int j = 0; j < 15; j++) {
            u64 prop = (lane < 4 && hq < 15) ? wl[lane][hq] : 0ULL;
            u64 m = prop;
            #pragma unroll
            for (int s = 32; s >= 1; s >>= 1) { u64 t = __shfl_xor(m, s, 64); if (t > m) m = t; }
            if (m != 0ULL && prop == m) hq++;
            if (lane == j) outk = m;
        }
        if (lane < 15) selk[lane] = outk;
    }
    __syncthreads();

    if (tid == 0) {
        float s = 0.0f;
        int pc = 0;
        #pragma unroll
        for (int j = 0; j < 15; j++) {
            float v = keyval(selk[j]);
            s += v;
            if (v > 0.0f) pc++;
        }
        int np = (int)s; if (np < 1) np = 1;
        s_num = np;
        if (pc == 0) {
            // empty row: top_k -> indices 0..14, num_pos=1 -> boost entry p=0
            u64 bk = ((u64)__float_as_uint(3.0f) << 32) | (u32)(~(u32)o);
            atomicMax(&bkey[(size_t)n * P + 0], bk);
            if (record) {
                u32 idx = atomicAdd(&pcnt[n], 1u);
                plistP[n * 256 + idx] = 0u;
                plistE[n * 256 + idx] = bk;
            }
            s_num = 0;
        }
    }
    __syncthreads();
    if (tid < 15 && tid < s_num) {
        u64 k = selk[tid];
        float v = keyval(k);
        if (v > 0.0f) {
            u32 pidx = ~(u32)(k & 0xFFFFFFFFULL);
            u64 bk = ((u64)__float_as_uint(v + 3.0f) << 32) | (u32)(~(u32)o);
            atomicMax(&bkey[(size_t)n * P + pidx], bk);
            if (record) {
                u32 idx = atomicAdd(&pcnt[n], 1u);
                plistP[n * 256 + idx] = pidx;
                plistE[n * 256 + idx] = bk;
            }
        }
    }
}

// ---------- K3: corrections for boosted anchors ----------
__global__ __launch_bounds__(256) void k_correct(
        const float* __restrict__ conf, const int* __restrict__ labels,
        const u64* __restrict__ ovkey, const u32* __restrict__ plistP,
        const u64* __restrict__ plistE, const u32* __restrict__ pcnt,
        double* __restrict__ partCC, u32* __restrict__ posCnt, int P) {
    int n = blockIdx.x, tid = threadIdx.x;
    __shared__ int lab[16];
    if (tid < 16) lab[tid] = labels[n * 16 + tid];
    __syncthreads();
    int cnt = (int)pcnt[n];
    float dsum = 0.0f;
    int mypos = 0;
    for (int t = tid; t < cnt; t += 256) {
        u32 p = plistP[n * 256 + t];
        u64 bk = plistE[n * 256 + t];
        u64 k = ovkey[(size_t)n * P + p];
        if (k == bk) {
            float v3 = keyval(k);
            float vt = v3 - 3.0f;
            if (vt > 0.0f) {
                mypos++;
                int o = (int)(~(u32)(k & 0xFFFFFFFFULL)) & 15;
                int tcls = lab[o];
                float lg = conf[((size_t)n * P + p) * 80 + tcls];
                float e  = fexp2(-fabsf(lg) * LOG2E);
                float ln1pe = flog2(1.0f + e) * LN2;
                float rc = frcp(1.0f + e);
                float sg = (lg >= 0.0f) ? rc : e * rc;
                float bce0 = fmaxf(lg, 0.0f) + ln1pe;
                float bce1 = fmaxf(lg, 0.0f) - lg * vt + ln1pe;
                float d1 = sg - vt;
                dsum += d1 * d1 * bce1 - sg * sg * bce0;
            }
        }
    }
    double dd = (double)dsum;
    long long pp = mypos;
    #pragma unroll
    for (int s = 32; s > 0; s >>= 1) { dd += __shfl_down(dd, s, 64); pp += __shfl_down(pp, s, 64); }
    __shared__ double wd[4];
    __shared__ long long wp[4];
    if ((tid & 63) == 0) { wd[tid >> 6] = dd; wp[tid >> 6] = pp; }
    __syncthreads();
    if (tid == 0) {
        partCC[n] = wd[0] + wd[1] + wd[2] + wd[3];
        posCnt[n] = (u32)(wp[0] + wp[1] + wp[2] + wp[3]);
    }
}

// ---------- K5: localization loss from predkey -> per-block slots ----------
__global__ __launch_bounds__(256) void k_loss_l(
        const u64* __restrict__ predkey, const float* __restrict__ loc,
        const float* __restrict__ priors, const float* __restrict__ truths,
        double* __restrict__ partL, double* __restrict__ partR, int P) {
    int n = blockIdx.y;
    int p = blockIdx.x * 256 + threadIdx.x;
    __shared__ float strt[64];
    if (threadIdx.x < 64) strt[threadIdx.x] = truths[n * 64 + threadIdx.x];
    __syncthreads();

    float r = 0.0f, contrib = 0.0f;
    if (p < P) {
        u64 k = predkey[(size_t)n * P + p];
        float pt = keyval(k);
        int best = (int)(~(u32)(k & 0xFFFFFFFFULL)) & 15;
        r = fmaxf(pt - 3.0f, 0.0f);
        if (r > 0.0f) {
            const float Bc   = (float)19.085536923187668;
            const float beta = 0.11f;
            float4 pr = *(const float4*)(priors + (size_t)p * 4);
            float tx1 = strt[best * 4],     ty1 = strt[best * 4 + 1];
            float tx2 = strt[best * 4 + 2], ty2 = strt[best * 4 + 3];
            float gcx = ((tx1 + tx2) * 0.5f - pr.x) / (0.1f * pr.z);
            float gcy = ((ty1 + ty2) * 0.5f - pr.y) / (0.1f * pr.w);
            float gw  = flog2((tx2 - tx1) / pr.z) * LN2 / 0.2f;
            float gh  = flog2((ty2 - ty1) / pr.w) * LN2 / 0.2f;
            float4 l  = *(const float4*)(loc + ((size_t)n * P + p) * 4);
            float tgt[4] = {gcx, gcy, gw, gh};
            float lvv[4] = {l.x, l.y, l.z, l.w};
            float s = 0.0f;
            #pragma unroll
            for (int j = 0; j < 4; j++) {
                float diff = fabsf(lvv[j] - tgt[j]);
                float bl;
                if (diff < beta) {
                    bl = 0.5f / Bc * (Bc * diff + 1.0f) * (flog2(1.0f + Bc * diff / beta) * LN2)
                         - 0.5f * diff;
                } else {
                    bl = 1.5f * diff + 1.5f / Bc - 0.5f * beta;
                }
                s += bl;
            }
            contrib = r * s;
        }
    }
    double dl = (double)contrib, dr = (double)r;
    #pragma unroll
    for (int s = 32; s > 0; s >>= 1) { dl += __shfl_down(dl, s, 64); dr += __shfl_down(dr, s, 64); }
    __shared__ double bl_[4], br_[4];
    int wid = threadIdx.x >> 6;
    if ((threadIdx.x & 63) == 0) { bl_[wid] = dl; br_[wid] = dr; }
    __syncthreads();
    if (threadIdx.x == 0) {
        size_t slot = (size_t)blockIdx.y * gridDim.x + blockIdx.x;
        partL[slot] = bl_[0] + bl_[1] + bl_[2] + bl_[3];
        partR[slot] = br_[0] + br_[1] + br_[2] + br_[3];
    }
}

// ---------- K6: final reduction ----------
__global__ __launch_bounds__(256) void k_fin(
        const double* __restrict__ partC, int nC, const double* __restrict__ partCC,
        const double* __restrict__ partL, const double* __restrict__ partR, int nL,
        const u32* __restrict__ posCnt, int N, float* __restrict__ out) {
    int tid = threadIdx.x;
    double sC = 0, sL = 0, sR = 0;
    long long pos = 0;
    for (int i = tid; i < nC; i += 256) sC += partC[i];
    for (int i = tid; i < nL; i += 256) { sL += partL[i]; sR += partR[i]; }
    for (int i = tid; i < N; i += 256) { sC += partCC[i]; pos += (long long)posCnt[i]; }
    #pragma unroll
    for (int s = 32; s > 0; s >>= 1) {
        sC += __shfl_down(sC, s, 64);
        sL += __shfl_down(sL, s, 64);
        sR += __shfl_down(sR, s, 64);
        pos += __shfl_down(pos, s, 64);
    }
    __shared__ double aC[4], aL[4], aR[4];
    __shared__ long long aP[4];
    int wv = tid >> 6;
    if ((tid & 63) == 0) { aC[wv] = sC; aL[wv] = sL; aR[wv] = sR; aP[wv] = pos; }
    __syncthreads();
    if (tid == 0) {
        double tC = aC[0] + aC[1] + aC[2] + aC[3];
        double tL = aL[0] + aL[1] + aL[2] + aL[3];
        double tR = aR[0] + aR[1] + aR[2] + aR[3];
        long long tP = aP[0] + aP[1] + aP[2] + aP[3];
        double npos = tP > 0 ? (double)tP : 1.0;
        out[0] = (float)(tL / (4.0 * tR));
        out[1] = (float)(tC / npos);
    }
}

extern "C" void kernel_launch(void* const* d_in, const int* in_sizes, int n_in,
                              void* d_out, int out_size, void* d_ws, size_t ws_size,
                              hipStream_t stream) {
    const float* loc    = (const float*)d_in[0];
    const float* conf   = (const float*)d_in[1];
    const float* priors = (const float*)d_in[2];
    const float* truths = (const float*)d_in[3];
    const int*   labels = (const int*)d_in[4];

    int P = in_sizes[2] / 4;                 // 18000
    int N = in_sizes[0] / (P * 4);           // 32
    int NBLK = (P + 63) / 64;                // 282
    int ROWS = N * 16;                       // 512
    int gridLx = (P + 255) / 256;            // 71
    int nC = NBLK * N;                       // 9024
    int nL = gridLx * N;                     // 2272
    // C == 80, O == 16 assumed by kernel tiling

    char* cur = (char*)d_ws;
    auto alloc = [&](size_t bytes) { char* r = cur; cur += (bytes + 255) & ~(size_t)255; return r; };
    u32* pcnt      = (u32*)alloc((size_t)N * 4);
    u32* posCnt    = (u32*)alloc((size_t)N * 4);
    double* partCC = (double*)alloc((size_t)N * 8);
    u32* plistP    = (u32*)alloc((size_t)N * 256 * 4);
    u64* plistE    = (u64*)alloc((size_t)N * 256 * 8);
    double* partC  = (double*)alloc((size_t)nC * 8);
    double* partL  = (double*)alloc((size_t)nL * 8);
    double* partR  = (double*)alloc((size_t)nL * 8);
    u64* basekeyR  = (u64*)alloc((size_t)N * P * 8);
    u64* ovkey     = (u64*)alloc((size_t)N * P * 8);
    u64* basekeyP  = (u64*)alloc((size_t)N * P * 8);
    u64* predkey   = (u64*)alloc((size_t)N * P * 8);
    float* out = (float*)d_out;

    dim3 blk(256);
    dim3 gridB(NBLK, N);
    dim3 gridS(ROWS, 2);
    dim3 gridL(gridLx, N);

    k_main<<<gridB, blk, 0, stream>>>(loc, conf, priors, truths, labels,
                                      basekeyR, ovkey, basekeyP, predkey,
                                      partC, pcnt, P);
    k_tsel<<<gridS, blk, 0, stream>>>(basekeyR, basekeyP, ovkey, predkey,
                                      plistP, plistE, pcnt, P);
    k_correct<<<N, blk, 0, stream>>>(conf, labels, ovkey, plistP, plistE, pcnt,
                                     partCC, posCnt, P);
    k_loss_l<<<gridL, blk, 0, stream>>>(predkey, loc, priors, truths, partL, partR, P);
    k_fin<<<1, blk, 0, stream>>>(partC, nC, partCC, partL, partR, nL, posCnt, N, out);
}

// Round 13
// 175.093 us; speedup vs baseline: 1.4140x; 1.4140x over previous
//
#include <hip/hip_runtime.h>
#include <hip/hip_bf16.h>

typedef unsigned long long u64;
typedef unsigned int u32;

#define LOG2E 1.44269504088896340736f
#define LN2   0.69314718055994530942f
#define NCH   8

// ---------- fast math ----------
__device__ __forceinline__ float fexp2(float x) { return __builtin_amdgcn_exp2f(x); }
__device__ __forceinline__ float flog2(float x) { return __builtin_amdgcn_logf(x); }
__device__ __forceinline__ float frcp(float x)  { return __builtin_amdgcn_rcpf(x); }
__device__ __forceinline__ float keyval(u64 k) { return __uint_as_float((u32)(k >> 32)); }

__device__ __forceinline__ float iou_xyxy(float ax1, float ay1, float ax2, float ay2,
                                          float bx1, float by1, float bx2, float by2) {
    float ltx = fmaxf(ax1, bx1), lty = fmaxf(ay1, by1);
    float rbx = fminf(ax2, bx2), rby = fminf(ay2, by2);
    float w = fmaxf(rbx - ltx, 0.0f), h = fmaxf(rby - lty, 0.0f);
    float inter = w * h;
    float areaA = (ax2 - ax1) * (ay2 - ay1);
    float areaB = (bx2 - bx1) * (by2 - by1);
    return inter / (areaA + areaB - inter);
}

// ---------- K1: fused main pass (reg path + gfocal stream + pred path) ----------
__global__ __launch_bounds__(256) void k_main(
        const float* __restrict__ loc, const float* __restrict__ conf,
        const float* __restrict__ priors, const float* __restrict__ truths,
        const int* __restrict__ labels,
        u64* __restrict__ basekeyR, u64* __restrict__ ovkey,
        u64* __restrict__ basekeyP, u64* __restrict__ predkey,
        double* __restrict__ partC, u32* __restrict__ pcnt, u32* __restrict__ pcnt2,
        int P) {
    int n = blockIdx.y, p0 = blockIdx.x * 64, tid = threadIdx.x;
    int r = tid >> 2, sub = tid & 3, p = p0 + r;
    bool act = p < P;

    if (blockIdx.x == 0 && tid == 0) { pcnt[n] = 0u; pcnt2[n] = 0u; }

    // issue ALL global loads first (in flight across LDS setup barriers)
    float4 L0, L1, L2, L3, L4, prv, lc;
    L0 = L1 = L2 = L3 = L4 = prv = lc = make_float4(0.f, 0.f, 0.f, 0.f);
    if (act) {
        const float* rowp = conf + ((size_t)n * P + p) * 80 + sub * 4;
        L0 = *(const float4*)(rowp);
        L1 = *(const float4*)(rowp + 16);
        L2 = *(const float4*)(rowp + 32);
        L3 = *(const float4*)(rowp + 48);
        L4 = *(const float4*)(rowp + 64);
        prv = *(const float4*)(priors + (size_t)p * 4);
        lc  = *(const float4*)(loc + ((size_t)n * P + p) * 4);
    }

    __shared__ float strt[64];
    __shared__ int   lab[16];
    __shared__ u32   smask[80];
    __shared__ float sglab[64][17];
    if (tid < 64) strt[tid] = truths[n * 64 + tid];
    if (tid < 80) smask[tid] = 0u;
    __syncthreads();
    if (tid < 16) {
        int lb = labels[n * 16 + tid];
        lab[tid] = lb;
        atomicOr(&smask[lb], 1u << tid);
    }
    __syncthreads();

    u32 mybits = 0;
    #pragma unroll
    for (int k = 0; k < 5; k++) {
        #pragma unroll
        for (int j = 0; j < 4; j++) {
            if (smask[k * 16 + sub * 4 + j]) mybits |= 1u << (k * 4 + j);
        }
    }

    // ---- reg path: decoded box IoUs -> basekeyR + ovkey
    {
        float vv[4] = {0, 0, 0, 0};
        u64 mykey = 0;
        if (act) {
            float cx = prv.x + lc.x * 0.1f * prv.z;
            float cy = prv.y + lc.y * 0.1f * prv.w;
            float w  = prv.z * fexp2(lc.z * 0.2f * LOG2E);
            float h  = prv.w * fexp2(lc.w * 0.2f * LOG2E);
            float bx1 = cx - w * 0.5f, by1 = cy - h * 0.5f;
            float bx2 = cx + w * 0.5f, by2 = cy + h * 0.5f;
            #pragma unroll
            for (int jj = 0; jj < 4; jj++) {
                int o = sub * 4 + jj;
                float v = iou_xyxy(strt[o * 4], strt[o * 4 + 1], strt[o * 4 + 2],
                                   strt[o * 4 + 3], bx1, by1, bx2, by2);
                vv[jj] = v;
                u64 kk = ((u64)__float_as_uint(v) << 32) | (u32)(~(u32)o);
                if (kk > mykey) mykey = kk;
            }
        }
        { u64 t = __shfl_xor(mykey, 1, 64); if (t > mykey) mykey = t;
          t = __shfl_xor(mykey, 2, 64); if (t > mykey) mykey = t; }
        float m = keyval(mykey);
        u32 bits = 0;
        #pragma unroll
        for (int jj = 0; jj < 4; jj++) {
            if (act && vv[jj] == m) bits |= 1u << (sub * 4 + jj);
        }
        bits |= __shfl_xor(bits, 1, 64);
        bits |= __shfl_xor(bits, 2, 64);
        if (act && sub == 0) {
            size_t idx = (size_t)n * P + p;
            basekeyR[idx] = ((u64)__float_as_uint(m) << 32) | bits;
            ovkey[idx]    = mykey;
        }
    }

    // ---- gfocal stream, t = 0 everywhere (corrections in k_correct)
    float lsum = 0.0f;
    if (act) {
        float lv[20] = {L0.x, L0.y, L0.z, L0.w, L1.x, L1.y, L1.z, L1.w,
                        L2.x, L2.y, L2.z, L2.w, L3.x, L3.y, L3.z, L3.w,
                        L4.x, L4.y, L4.z, L4.w};
        #pragma unroll
        for (int k = 0; k < 5; k++) {
            #pragma unroll
            for (int j = 0; j < 4; j++) {
                float lg = lv[k * 4 + j];
                float e  = fexp2(-fabsf(lg) * LOG2E);
                float ln1pe = flog2(1.0f + e) * LN2;
                float rc = frcp(1.0f + e);
                float sg = (lg >= 0.0f) ? rc : e * rc;
                lsum += sg * sg * (fmaxf(lg, 0.0f) + ln1pe);
                if (mybits & (1u << (k * 4 + j))) {
                    u32 m16 = smask[k * 16 + sub * 4 + j];
                    while (m16) {
                        int o = __ffs(m16) - 1;
                        sglab[r][o] = sg;
                        m16 &= m16 - 1;
                    }
                }
            }
        }
    }
    __syncthreads();

    // ---- pred path: prior-box IoUs + sglab -> basekeyP + predkey
    {
        float pv[4] = {0, 0, 0, 0};
        u64 pkey = 0;
        if (act) {
            float px1 = prv.x - prv.z * 0.5f, py1 = prv.y - prv.w * 0.5f;
            float px2 = prv.x + prv.z * 0.5f, py2 = prv.y + prv.w * 0.5f;
            #pragma unroll
            for (int jj = 0; jj < 4; jj++) {
                int o = sub * 4 + jj;
                float ov = iou_xyxy(strt[o * 4], strt[o * 4 + 1], strt[o * 4 + 2],
                                    strt[o * 4 + 3], px1, py1, px2, py2);
                float pd = 0.0f;
                if (ov > 0.0f) {
                    float pc = sglab[r][o];
                    pd = fexp2((2.0f - pc) * 0.5f * flog2(ov));
                }
                pv[jj] = pd;
                u64 kk = ((u64)__float_as_uint(pd) << 32) | (u32)(~(u32)o);
                if (kk > pkey) pkey = kk;
            }
        }
        { u64 t = __shfl_xor(pkey, 1, 64); if (t > pkey) pkey = t;
          t = __shfl_xor(pkey, 2, 64); if (t > pkey) pkey = t; }
        float pm = keyval(pkey);
        u32 bits = 0;
        #pragma unroll
        for (int jj = 0; jj < 4; jj++) {
            if (act && pv[jj] == pm) bits |= 1u << (sub * 4 + jj);
        }
        bits |= __shfl_xor(bits, 1, 64);
        bits |= __shfl_xor(bits, 2, 64);
        if (act && sub == 0) {
            size_t idx = (size_t)n * P + p;
            basekeyP[idx] = ((u64)__float_as_uint(pm) << 32) | bits;
            predkey[idx]  = pkey;
        }
    }

    // ---- block reduce gfocal partials -> per-block slot (no atomic)
    #pragma unroll
    for (int s = 32; s > 0; s >>= 1) lsum += __shfl_down(lsum, s, 64);
    __shared__ float wsum[4];
    if ((tid & 63) == 0) wsum[tid >> 6] = lsum;
    __syncthreads();
    if (tid == 0) {
        partC[(size_t)blockIdx.y * gridDim.x + blockIdx.x] =
            (double)wsum[0] + (double)wsum[1] + (double)wsum[2] + (double)wsum[3];
    }
}

// ---------- K2a: per-(chunk,row,z) partial top-15, single wave, register-only ---------
__global__ __launch_bounds__(64) void k_tpart(
        const u64* __restrict__ basekeyR, const u64* __restrict__ basekeyP,
        u64* __restrict__ cand, int P, int CH, int ROWS) {
    int c = blockIdx.x, row = blockIdx.y, z = blockIdx.z;
    int n = row >> 4, o = row & 15;
    int lane = threadIdx.x;
    int pend = c * CH + CH; if (pend > P) pend = P;
    const u64* base = (z ? basekeyP : basekeyR) + (size_t)n * P;

    u64 lv[15];
    #pragma unroll
    for (int k = 0; k < 15; k++) lv[k] = 0;

    for (int p = c * CH + lane; p < pend; p += 64) {
        u64 b = base[p];
        if ((u32)(b >> 32) != 0u && ((b >> o) & 1)) {
            u64 key = (b & 0xFFFFFFFF00000000ULL) | (u32)(~(u32)p);
            if (key > lv[14]) {
                #pragma unroll
                for (int k = 14; k >= 0; k--) {
                    bool shift = (k > 0) && (key > lv[k - 1]);
                    if (shift)            lv[k] = lv[k - 1];
                    else if (key > lv[k]) lv[k] = key;
                }
            }
        }
    }

    // 15 extraction rounds: wave-max of lv[0]; unique winner pops (register shift).
    u64 mine = 0;
    for (int j = 0; j < 15; j++) {
        u64 m = lv[0];
        #pragma unroll
        for (int s = 32; s >= 1; s >>= 1) { u64 t = __shfl_xor(m, s, 64); if (t > m) m = t; }
        bool win = (m != 0ULL) && (lv[0] == m);
        if (win) {
            #pragma unroll
            for (int k = 0; k < 14; k++) lv[k] = lv[k + 1];
            lv[14] = 0;
        }
        if (lane == j) mine = m;
    }
    if (lane < 15)
        cand[(((size_t)z * ROWS + row) * NCH + c) * 15 + lane] = mine;
}

// ---------- K2b: merge NCH partial lists -> top-15, num_pos, boost + record ----------
__global__ __launch_bounds__(64) void k_tmerge(
        const u64* __restrict__ cand, u64* __restrict__ ovkey, u64* __restrict__ predkey,
        u32* __restrict__ plistP, u64* __restrict__ plistE, u32* __restrict__ pcnt,
        u32* __restrict__ plistP2, u64* __restrict__ plistE2, u32* __restrict__ pcnt2,
        int P, int ROWS) {
    int row = blockIdx.x, z = blockIdx.y, tid = threadIdx.x;
    int n = row >> 4, o = row & 15;
    u64* bkey = z ? predkey : ovkey;
    u32* lp = z ? plistP2 : plistP;
    u64* le = z ? plistE2 : plistE;
    u32* lc = z ? pcnt2 : pcnt;
    __shared__ u64 sk[NCH * 15];
    for (int i = tid; i < NCH * 15; i += 64)
        sk[i] = cand[((size_t)z * ROWS + row) * NCH * 15 + i];
    __syncthreads();

    __shared__ u64 selk[15];
    __shared__ int s_num;
    int hp = 0;
    for (int j = 0; j < 15; j++) {
        u64 prop = (tid < NCH && hp < 15) ? sk[tid * 15 + hp] : 0ULL;
        u64 m = prop;
        #pragma unroll
        for (int s = 32; s >= 1; s >>= 1) { u64 t = __shfl_xor(m, s, 64); if (t > m) m = t; }
        if (m != 0ULL && prop == m) hp++;
        if (tid == 0) selk[j] = m;
    }
    __syncthreads();

    if (tid == 0) {
        float s = 0.0f;
        int pc = 0;
        #pragma unroll
        for (int j = 0; j < 15; j++) {
            float v = keyval(selk[j]);
            s += v;
            if (v > 0.0f) pc++;
        }
        int np = (int)s; if (np < 1) np = 1;
        s_num = np;
        if (pc == 0) {
            // empty row: top_k -> indices 0..14, num_pos=1 -> boost entry p=0
            u64 bk = ((u64)__float_as_uint(3.0f) << 32) | (u32)(~(u32)o);
            atomicMax(&bkey[(size_t)n * P + 0], bk);
            u32 idx = atomicAdd(&lc[n], 1u);
            lp[n * 256 + idx] = 0u;
            le[n * 256 + idx] = bk;
            s_num = 0;
        }
    }
    __syncthreads();
    if (tid < 15 && tid < s_num) {
        u64 k = selk[tid];
        float v = keyval(k);
        if (v > 0.0f) {
            u32 pidx = ~(u32)(k & 0xFFFFFFFFULL);
            u64 bk = ((u64)__float_as_uint(v + 3.0f) << 32) | (u32)(~(u32)o);
            atomicMax(&bkey[(size_t)n * P + pidx], bk);
            u32 idx = atomicAdd(&lc[n], 1u);
            lp[n * 256 + idx] = pidx;
            le[n * 256 + idx] = bk;
        }
    }
}

// ---------- K3: corrections for boosted anchors (reg path) ----------
__global__ __launch_bounds__(256) void k_correct(
        const float* __restrict__ conf, const int* __restrict__ labels,
        const u64* __restrict__ ovkey, const u32* __restrict__ plistP,
        const u64* __restrict__ plistE, const u32* __restrict__ pcnt,
        double* __restrict__ partCC, u32* __restrict__ posCnt, int P) {
    int n = blockIdx.x, tid = threadIdx.x;
    __shared__ int lab[16];
    if (tid < 16) lab[tid] = labels[n * 16 + tid];
    __syncthreads();
    int cnt = (int)pcnt[n];
    float dsum = 0.0f;
    int mypos = 0;
    for (int t = tid; t < cnt; t += 256) {
        u32 p = plistP[n * 256 + t];
        u64 bk = plistE[n * 256 + t];
        u64 k = ovkey[(size_t)n * P + p];
        if (k == bk) {
            float v3 = keyval(k);
            float vt = v3 - 3.0f;
            if (vt > 0.0f) {
                mypos++;
                int o = (int)(~(u32)(k & 0xFFFFFFFFULL)) & 15;
                int tcls = lab[o];
                float lg = conf[((size_t)n * P + p) * 80 + tcls];
                float e  = fexp2(-fabsf(lg) * LOG2E);
                float ln1pe = flog2(1.0f + e) * LN2;
                float rc = frcp(1.0f + e);
                float sg = (lg >= 0.0f) ? rc : e * rc;
                float bce0 = fmaxf(lg, 0.0f) + ln1pe;
                float bce1 = fmaxf(lg, 0.0f) - lg * vt + ln1pe;
                float d1 = sg - vt;
                dsum += d1 * d1 * bce1 - sg * sg * bce0;
            }
        }
    }
    double dd = (double)dsum;
    long long pp = mypos;
    #pragma unroll
    for (int s = 32; s > 0; s >>= 1) { dd += __shfl_down(dd, s, 64); pp += __shfl_down(pp, s, 64); }
    __shared__ double wd[4];
    __shared__ long long wp[4];
    if ((tid & 63) == 0) { wd[tid >> 6] = dd; wp[tid >> 6] = pp; }
    __syncthreads();
    if (tid == 0) {
        partCC[n] = wd[0] + wd[1] + wd[2] + wd[3];
        posCnt[n] = (u32)(wp[0] + wp[1] + wp[2] + wp[3]);
    }
}

// ---------- K5: localization loss over pred-boost list only ----------
// relu(pred_t-3) > 0 only for boosted anchors, so only the list contributes.
__global__ __launch_bounds__(256) void k_loss_l(
        const u64* __restrict__ predkey, const float* __restrict__ loc,
        const float* __restrict__ priors, const float* __restrict__ truths,
        const u32* __restrict__ plistP2, const u64* __restrict__ plistE2,
        const u32* __restrict__ pcnt2,
        double* __restrict__ partL, double* __restrict__ partR, int P) {
    int n = blockIdx.x, tid = threadIdx.x;
    __shared__ float strt[64];
    if (tid < 64) strt[tid] = truths[n * 64 + tid];
    __syncthreads();
    int cnt = (int)pcnt2[n];
    float rsum = 0.0f, csum = 0.0f;
    for (int t = tid; t < cnt; t += 256) {
        u32 p = plistP2[n * 256 + t];
        u64 bk = plistE2[n * 256 + t];
        u64 k = predkey[(size_t)n * P + p];
        if (k == bk) {                         // this entry owns the final key
            float pt = keyval(k);
            float r = pt - 3.0f;
            if (r > 0.0f) {
                int best = (int)(~(u32)(k & 0xFFFFFFFFULL)) & 15;
                const float Bc   = (float)19.085536923187668;
                const float beta = 0.11f;
                float4 pr = *(const float4*)(priors + (size_t)p * 4);
                float tx1 = strt[best * 4],     ty1 = strt[best * 4 + 1];
                float tx2 = strt[best * 4 + 2], ty2 = strt[best * 4 + 3];
                float gcx = ((tx1 + tx2) * 0.5f - pr.x) / (0.1f * pr.z);
                float gcy = ((ty1 + ty2) * 0.5f - pr.y) / (0.1f * pr.w);
                float gw  = flog2((tx2 - tx1) / pr.z) * LN2 / 0.2f;
                float gh  = flog2((ty2 - ty1) / pr.w) * LN2 / 0.2f;
                float4 l  = *(const float4*)(loc + ((size_t)n * P + p) * 4);
                float tgt[4] = {gcx, gcy, gw, gh};
                float lvv[4] = {l.x, l.y, l.z, l.w};
                float s = 0.0f;
                #pragma unroll
                for (int j = 0; j < 4; j++) {
                    float diff = fabsf(lvv[j] - tgt[j]);
                    float bl;
                    if (diff < beta) {
                        bl = 0.5f / Bc * (Bc * diff + 1.0f) *
                             (flog2(1.0f + Bc * diff / beta) * LN2) - 0.5f * diff;
                    } else {
                        bl = 1.5f * diff + 1.5f / Bc - 0.5f * beta;
                    }
                    s += bl;
                }
                rsum += r;
                csum += r * s;
            }
        }
    }
    double dl = (double)csum, dr = (double)rsum;
    #pragma unroll
    for (int s = 32; s > 0; s >>= 1) { dl += __shfl_down(dl, s, 64); dr += __shfl_down(dr, s, 64); }
    __shared__ double bl_[4], br_[4];
    int wid = tid >> 6;
    if ((tid & 63) == 0) { bl_[wid] = dl; br_[wid] = dr; }
    __syncthreads();
    if (tid == 0) {
        partL[n] = bl_[0] + bl_[1] + bl_[2] + bl_[3];
        partR[n] = br_[0] + br_[1] + br_[2] + br_[3];
    }
}

// ---------- K6: final reduction ----------
__global__ __launch_bounds__(256) void k_fin(
        const double* __restrict__ partC, int nC, const double* __restrict__ partCC,
        const double* __restrict__ partL, const double* __restrict__ partR,
        const u32* __restrict__ posCnt, int N, float* __restrict__ out) {
    int tid = threadIdx.x;
    double sC = 0, sL = 0, sR = 0;
    long long pos = 0;
    for (int i = tid; i < nC; i += 256) sC += partC[i];
    for (int i = tid; i < N; i += 256) {
        sC += partCC[i]; sL += partL[i]; sR += partR[i];
        pos += (long long)posCnt[i];
    }
    #pragma unroll
    for (int s = 32; s > 0; s >>= 1) {
        sC += __shfl_down(sC, s, 64);
        sL += __shfl_down(sL, s, 64);
        sR += __shfl_down(sR, s, 64);
        pos += __shfl_down(pos, s, 64);
    }
    __shared__ double aC[4], aL[4], aR[4];
    __shared__ long long aP[4];
    int wv = tid >> 6;
    if ((tid & 63) == 0) { aC[wv] = sC; aL[wv] = sL; aR[wv] = sR; aP[wv] = pos; }
    __syncthreads();
    if (tid == 0) {
        double tC = aC[0] + aC[1] + aC[2] + aC[3];
        double tL = aL[0] + aL[1] + aL[2] + aL[3];
        double tR = aR[0] + aR[1] + aR[2] + aR[3];
        long long tP = aP[0] + aP[1] + aP[2] + aP[3];
        double npos = tP > 0 ? (double)tP : 1.0;
        out[0] = (float)(tL / (4.0 * tR));
        out[1] = (float)(tC / npos);
    }
}

extern "C" void kernel_launch(void* const* d_in, const int* in_sizes, int n_in,
                              void* d_out, int out_size, void* d_ws, size_t ws_size,
                              hipStream_t stream) {
    const float* loc    = (const float*)d_in[0];
    const float* conf   = (const float*)d_in[1];
    const float* priors = (const float*)d_in[2];
    const float* truths = (const float*)d_in[3];
    const int*   labels = (const int*)d_in[4];

    int P = in_sizes[2] / 4;                 // 18000
    int N = in_sizes[0] / (P * 4);           // 32
    int NBLK = (P + 63) / 64;                // 282
    int CH   = (P + NCH - 1) / NCH;          // 2250
    int ROWS = N * 16;                       // 512
    int nC = NBLK * N;                       // 9024
    // C == 80, O == 16 assumed by kernel tiling

    char* cur = (char*)d_ws;
    auto alloc = [&](size_t bytes) { char* r = cur; cur += (bytes + 255) & ~(size_t)255; return r; };
    u32* pcnt      = (u32*)alloc((size_t)N * 4);
    u32* pcnt2     = (u32*)alloc((size_t)N * 4);
    u32* posCnt    = (u32*)alloc((size_t)N * 4);
    double* partCC = (double*)alloc((size_t)N * 8);
    u32* plistP    = (u32*)alloc((size_t)N * 256 * 4);
    u64* plistE    = (u64*)alloc((size_t)N * 256 * 8);
    u32* plistP2   = (u32*)alloc((size_t)N * 256 * 4);
    u64* plistE2   = (u64*)alloc((size_t)N * 256 * 8);
    double* partC  = (double*)alloc((size_t)nC * 8);
    double* partL  = (double*)alloc((size_t)N * 8);
    double* partR  = (double*)alloc((size_t)N * 8);
    u64* cand      = (u64*)alloc((size_t)2 * ROWS * NCH * 15 * 8);
    u64* basekeyR  = (u64*)alloc((size_t)N * P * 8);
    u64* ovkey     = (u64*)alloc((size_t)N * P * 8);
    u64* basekeyP  = (u64*)alloc((size_t)N * P * 8);
    u64* predkey   = (u64*)alloc((size_t)N * P * 8);
    float* out = (float*)d_out;

    dim3 blk(256);
    dim3 gridB(NBLK, N);
    dim3 gridT(NCH, ROWS, 2);
    dim3 gridM(ROWS, 2);

    k_main<<<gridB, blk, 0, stream>>>(loc, conf, priors, truths, labels,
                                      basekeyR, ovkey, basekeyP, predkey,
                                      partC, pcnt, pcnt2, P);
    k_tpart<<<gridT, 64, 0, stream>>>(basekeyR, basekeyP, cand, P, CH, ROWS);
    k_tmerge<<<gridM, 64, 0, stream>>>(cand, ovkey, predkey,
                                       plistP, plistE, pcnt,
                                       plistP2, plistE2, pcnt2, P, ROWS);
    k_correct<<<N, blk, 0, stream>>>(conf, labels, ovkey, plistP, plistE, pcnt,
                                     partCC, posCnt, P);
    k_loss_l<<<N, blk, 0, stream>>>(predkey, loc, priors, truths,
                                    plistP2, plistE2, pcnt2, partL, partR, P);
    k_fin<<<1, blk, 0, stream>>>(partC, nC, partCC, partL, partR, posCnt, N, out);
}

// Round 14
// 174.125 us; speedup vs baseline: 1.4219x; 1.0056x over previous
//
#include <hip/hip_runtime.h>
#include <hip/hip_bf16.h>

typedef unsigned long long u64;
typedef unsigned int u32;

#define LOG2E 1.44269504088896340736f
#define LN2   0.69314718055994530942f
#define NCH   8

// ---------- fast math ----------
__device__ __forceinline__ float fexp2(float x) { return __builtin_amdgcn_exp2f(x); }
__device__ __forceinline__ float flog2(float x) { return __builtin_amdgcn_logf(x); }
__device__ __forceinline__ float frcp(float x)  { return __builtin_amdgcn_rcpf(x); }
__device__ __forceinline__ float keyval(u64 k) { return __uint_as_float((u32)(k >> 32)); }

__device__ __forceinline__ float iou_xyxy(float ax1, float ay1, float ax2, float ay2,
                                          float bx1, float by1, float bx2, float by2) {
    float ltx = fmaxf(ax1, bx1), lty = fmaxf(ay1, by1);
    float rbx = fminf(ax2, bx2), rby = fminf(ay2, by2);
    float w = fmaxf(rbx - ltx, 0.0f), h = fmaxf(rby - lty, 0.0f);
    float inter = w * h;
    float areaA = (ax2 - ax1) * (ay2 - ay1);
    float areaB = (bx2 - bx1) * (by2 - by1);
    return inter / (areaA + areaB - inter);
}

// ---------- K1: fused main pass (reg path + gfocal stream + pred path) ----------
__global__ __launch_bounds__(256) void k_main(
        const float* __restrict__ loc, const float* __restrict__ conf,
        const float* __restrict__ priors, const float* __restrict__ truths,
        const int* __restrict__ labels,
        u64* __restrict__ basekeyR, u64* __restrict__ basekeyP,
        double* __restrict__ partC, u32* __restrict__ pcnt, u32* __restrict__ pcnt2,
        int P) {
    int n = blockIdx.y, p0 = blockIdx.x * 64, tid = threadIdx.x;
    int r = tid >> 2, sub = tid & 3, p = p0 + r;
    bool act = p < P;

    if (blockIdx.x == 0 && tid == 0) { pcnt[n] = 0u; pcnt2[n] = 0u; }

    // issue ALL global loads first (in flight across LDS setup barriers)
    float4 L0, L1, L2, L3, L4, prv, lc;
    L0 = L1 = L2 = L3 = L4 = prv = lc = make_float4(0.f, 0.f, 0.f, 0.f);
    if (act) {
        const float* rowp = conf + ((size_t)n * P + p) * 80 + sub * 4;
        L0 = *(const float4*)(rowp);
        L1 = *(const float4*)(rowp + 16);
        L2 = *(const float4*)(rowp + 32);
        L3 = *(const float4*)(rowp + 48);
        L4 = *(const float4*)(rowp + 64);
        prv = *(const float4*)(priors + (size_t)p * 4);
        lc  = *(const float4*)(loc + ((size_t)n * P + p) * 4);
    }

    __shared__ float strt[64];
    __shared__ int   lab[16];
    __shared__ u32   smask[80];
    __shared__ float sglab[64][17];
    if (tid < 64) strt[tid] = truths[n * 64 + tid];
    if (tid < 80) smask[tid] = 0u;
    __syncthreads();
    if (tid < 16) {
        int lb = labels[n * 16 + tid];
        lab[tid] = lb;
        atomicOr(&smask[lb], 1u << tid);
    }
    __syncthreads();

    u32 mybits = 0;
    #pragma unroll
    for (int k = 0; k < 5; k++) {
        #pragma unroll
        for (int j = 0; j < 4; j++) {
            if (smask[k * 16 + sub * 4 + j]) mybits |= 1u << (k * 4 + j);
        }
    }

    // ---- reg path: decoded box IoUs -> basekeyR (colmax | tie-mask)
    {
        float vv[4] = {0, 0, 0, 0};
        float vmax = 0.0f;
        if (act) {
            float cx = prv.x + lc.x * 0.1f * prv.z;
            float cy = prv.y + lc.y * 0.1f * prv.w;
            float w  = prv.z * fexp2(lc.z * 0.2f * LOG2E);
            float h  = prv.w * fexp2(lc.w * 0.2f * LOG2E);
            float bx1 = cx - w * 0.5f, by1 = cy - h * 0.5f;
            float bx2 = cx + w * 0.5f, by2 = cy + h * 0.5f;
            #pragma unroll
            for (int jj = 0; jj < 4; jj++) {
                int o = sub * 4 + jj;
                float v = iou_xyxy(strt[o * 4], strt[o * 4 + 1], strt[o * 4 + 2],
                                   strt[o * 4 + 3], bx1, by1, bx2, by2);
                vv[jj] = v;
                vmax = fmaxf(vmax, v);
            }
        }
        vmax = fmaxf(vmax, __shfl_xor(vmax, 1, 64));
        vmax = fmaxf(vmax, __shfl_xor(vmax, 2, 64));
        u32 bits = 0;
        #pragma unroll
        for (int jj = 0; jj < 4; jj++) {
            if (act && vv[jj] == vmax) bits |= 1u << (sub * 4 + jj);
        }
        bits |= __shfl_xor(bits, 1, 64);
        bits |= __shfl_xor(bits, 2, 64);
        if (act && sub == 0) {
            basekeyR[(size_t)n * P + p] = ((u64)__float_as_uint(vmax) << 32) | bits;
        }
    }

    // ---- gfocal stream, t = 0 everywhere (corrections in k_tail)
    float lsum = 0.0f;
    if (act) {
        float lv[20] = {L0.x, L0.y, L0.z, L0.w, L1.x, L1.y, L1.z, L1.w,
                        L2.x, L2.y, L2.z, L2.w, L3.x, L3.y, L3.z, L3.w,
                        L4.x, L4.y, L4.z, L4.w};
        #pragma unroll
        for (int k = 0; k < 5; k++) {
            #pragma unroll
            for (int j = 0; j < 4; j++) {
                float lg = lv[k * 4 + j];
                float e  = fexp2(-fabsf(lg) * LOG2E);
                float ln1pe = flog2(1.0f + e) * LN2;
                float rc = frcp(1.0f + e);
                float sg = (lg >= 0.0f) ? rc : e * rc;
                lsum += sg * sg * (fmaxf(lg, 0.0f) + ln1pe);
                if (mybits & (1u << (k * 4 + j))) {
                    u32 m16 = smask[k * 16 + sub * 4 + j];
                    while (m16) {
                        int o = __ffs(m16) - 1;
                        sglab[r][o] = sg;
                        m16 &= m16 - 1;
                    }
                }
            }
        }
    }
    __syncthreads();

    // ---- pred path: prior-box IoUs + sglab -> basekeyP
    {
        float pv[4] = {0, 0, 0, 0};
        float pmax = 0.0f;
        if (act) {
            float px1 = prv.x - prv.z * 0.5f, py1 = prv.y - prv.w * 0.5f;
            float px2 = prv.x + prv.z * 0.5f, py2 = prv.y + prv.w * 0.5f;
            #pragma unroll
            for (int jj = 0; jj < 4; jj++) {
                int o = sub * 4 + jj;
                float ov = iou_xyxy(strt[o * 4], strt[o * 4 + 1], strt[o * 4 + 2],
                                    strt[o * 4 + 3], px1, py1, px2, py2);
                float pd = 0.0f;
                if (ov > 0.0f) {
                    float pc = sglab[r][o];
                    pd = fexp2((2.0f - pc) * 0.5f * flog2(ov));
                }
                pv[jj] = pd;
                pmax = fmaxf(pmax, pd);
            }
        }
        pmax = fmaxf(pmax, __shfl_xor(pmax, 1, 64));
        pmax = fmaxf(pmax, __shfl_xor(pmax, 2, 64));
        u32 bits = 0;
        #pragma unroll
        for (int jj = 0; jj < 4; jj++) {
            if (act && pv[jj] == pmax) bits |= 1u << (sub * 4 + jj);
        }
        bits |= __shfl_xor(bits, 1, 64);
        bits |= __shfl_xor(bits, 2, 64);
        if (act && sub == 0) {
            basekeyP[(size_t)n * P + p] = ((u64)__float_as_uint(pmax) << 32) | bits;
        }
    }

    // ---- block reduce gfocal partials -> per-block slot (no atomic)
    #pragma unroll
    for (int s = 32; s > 0; s >>= 1) lsum += __shfl_down(lsum, s, 64);
    __shared__ float wsum[4];
    if ((tid & 63) == 0) wsum[tid >> 6] = lsum;
    __syncthreads();
    if (tid == 0) {
        partC[(size_t)blockIdx.y * gridDim.x + blockIdx.x] =
            (double)wsum[0] + (double)wsum[1] + (double)wsum[2] + (double)wsum[3];
    }
}

// ---------- sorted-15 register insert ----------
__device__ __forceinline__ void ins15(u64* lv, u64 key) {
    if (key > lv[14]) {
        #pragma unroll
        for (int k = 14; k >= 0; k--) {
            bool shift = (k > 0) && (key > lv[k - 1]);
            if (shift)            lv[k] = lv[k - 1];
            else if (key > lv[k]) lv[k] = key;
        }
    }
}

// ---------- K2a: per-(chunk,row,z) partial top-15, single wave, register-only ---------
__global__ __launch_bounds__(64) void k_tpart(
        const u64* __restrict__ basekeyR, const u64* __restrict__ basekeyP,
        u64* __restrict__ cand, int P, int CH, int ROWS) {
    int c = blockIdx.x, row = blockIdx.y, z = blockIdx.z;
    int n = row >> 4, o = row & 15;
    int lane = threadIdx.x;
    int i0 = c * CH;
    int cnt = P - i0; if (cnt > CH) cnt = CH;
    const u64* base = (z ? basekeyP : basekeyR) + (size_t)n * P + i0;

    u64 lv[15];
    #pragma unroll
    for (int k = 0; k < 15; k++) lv[k] = 0;

    // 16B vectorized scan (alignment: i0 even, base 16B-aligned)
    for (int i = lane * 2; i < cnt; i += 128) {
        u64 b0, b1 = 0;
        bool two = (i + 1 < cnt);
        if (two) {
            ulonglong2 v = *(const ulonglong2*)(base + i);
            b0 = v.x; b1 = v.y;
        } else {
            b0 = base[i];
        }
        if ((u32)(b0 >> 32) != 0u && ((b0 >> o) & 1)) {
            ins15(lv, (b0 & 0xFFFFFFFF00000000ULL) | (u32)(~(u32)(i0 + i)));
        }
        if (two && (u32)(b1 >> 32) != 0u && ((b1 >> o) & 1)) {
            ins15(lv, (b1 & 0xFFFFFFFF00000000ULL) | (u32)(~(u32)(i0 + i + 1)));
        }
    }

    // 15 extraction rounds: wave-max of lv[0]; unique winner pops (register shift).
    u64 mine = 0;
    for (int j = 0; j < 15; j++) {
        u64 m = lv[0];
        #pragma unroll
        for (int s = 32; s >= 1; s >>= 1) { u64 t = __shfl_xor(m, s, 64); if (t > m) m = t; }
        bool win = (m != 0ULL) && (lv[0] == m);
        if (win) {
            #pragma unroll
            for (int k = 0; k < 14; k++) lv[k] = lv[k + 1];
            lv[14] = 0;
        }
        if (lane == j) mine = m;
    }
    if (lane < 15)
        cand[(((size_t)z * ROWS + row) * NCH + c) * 15 + lane] = mine;
}

// ---------- K2b: merge NCH partial lists -> top-15, num_pos, boost in-place ----------
__global__ __launch_bounds__(64) void k_tmerge(
        const u64* __restrict__ cand, u64* __restrict__ basekeyR, u64* __restrict__ basekeyP,
        u32* __restrict__ plistP, u64* __restrict__ plistE, u32* __restrict__ pcnt,
        u32* __restrict__ plistP2, u64* __restrict__ plistE2, u32* __restrict__ pcnt2,
        int P, int ROWS) {
    int row = blockIdx.x, z = blockIdx.y, tid = threadIdx.x;
    int n = row >> 4, o = row & 15;
    u64* bkey = z ? basekeyP : basekeyR;
    u32* lp = z ? plistP2 : plistP;
    u64* le = z ? plistE2 : plistE;
    u32* lc = z ? pcnt2 : pcnt;
    __shared__ u64 sk[NCH * 15];
    for (int i = tid; i < NCH * 15; i += 64)
        sk[i] = cand[((size_t)z * ROWS + row) * NCH * 15 + i];
    __syncthreads();

    __shared__ u64 selk[15];
    __shared__ int s_num;
    int hp = 0;
    for (int j = 0; j < 15; j++) {
        u64 prop = (tid < NCH && hp < 15) ? sk[tid * 15 + hp] : 0ULL;
        u64 m = prop;
        #pragma unroll
        for (int s = 32; s >= 1; s >>= 1) { u64 t = __shfl_xor(m, s, 64); if (t > m) m = t; }
        if (m != 0ULL && prop == m) hp++;
        if (tid == 0) selk[j] = m;
    }
    __syncthreads();

    if (tid == 0) {
        float s = 0.0f;
        int pc = 0;
        #pragma unroll
        for (int j = 0; j < 15; j++) {
            float v = keyval(selk[j]);
            s += v;
            if (v > 0.0f) pc++;
        }
        int np = (int)s; if (np < 1) np = 1;
        s_num = np;
        if (pc == 0) {
            // empty row: top_k -> indices 0..14, num_pos=1 -> boost entry p=0
            u64 bk = ((u64)__float_as_uint(3.0f) << 32) | (u32)(~(u32)o);
            atomicMax(&bkey[(size_t)n * P + 0], bk);
            u32 idx = atomicAdd(&lc[n], 1u);
            lp[n * 256 + idx] = 0u;
            le[n * 256 + idx] = bk;
            s_num = 0;
        }
    }
    __syncthreads();
    if (tid < 15 && tid < s_num) {
        u64 k = selk[tid];
        float v = keyval(k);
        if (v > 0.0f) {
            u32 pidx = ~(u32)(k & 0xFFFFFFFFULL);
            u64 bk = ((u64)__float_as_uint(v + 3.0f) << 32) | (u32)(~(u32)o);
            atomicMax(&bkey[(size_t)n * P + pidx], bk);
            u32 idx = atomicAdd(&lc[n], 1u);
            lp[n * 256 + idx] = pidx;
            le[n * 256 + idx] = bk;
        }
    }
}

// ---------- K3: fused tail — gfocal corrections + posCount + localization loss -------
__global__ __launch_bounds__(256) void k_tail(
        const float* __restrict__ conf, const float* __restrict__ loc,
        const float* __restrict__ priors, const float* __restrict__ truths,
        const int* __restrict__ labels,
        const u64* __restrict__ bkeyR, const u64* __restrict__ bkeyP,
        const u32* __restrict__ plistP, const u64* __restrict__ plistE,
        const u32* __restrict__ pcnt,
        const u32* __restrict__ plistP2, const u64* __restrict__ plistE2,
        const u32* __restrict__ pcnt2,
        double* __restrict__ partCC, u32* __restrict__ posCnt,
        double* __restrict__ partL, double* __restrict__ partR, int P) {
    int n = blockIdx.x, tid = threadIdx.x;
    __shared__ int lab[16];
    __shared__ float strt[64];
    if (tid < 16) lab[tid] = labels[n * 16 + tid];
    if (tid < 64) strt[tid] = truths[n * 64 + tid];
    __syncthreads();

    // ---- phase A: gfocal corrections over reg-boost list
    int cnt = (int)pcnt[n];
    float dsum = 0.0f;
    int mypos = 0;
    for (int t = tid; t < cnt; t += 256) {
        u32 p = plistP[n * 256 + t];
        u64 bk = plistE[n * 256 + t];
        u64 k = bkeyR[(size_t)n * P + p];
        if (k == bk) {
            float v3 = keyval(k);
            float vt = v3 - 3.0f;
            if (vt > 0.0f) {
                mypos++;
                int o = (int)(~(u32)(k & 0xFFFFFFFFULL)) & 15;
                int tcls = lab[o];
                float lg = conf[((size_t)n * P + p) * 80 + tcls];
                float e  = fexp2(-fabsf(lg) * LOG2E);
                float ln1pe = flog2(1.0f + e) * LN2;
                float rc = frcp(1.0f + e);
                float sg = (lg >= 0.0f) ? rc : e * rc;
                float bce0 = fmaxf(lg, 0.0f) + ln1pe;
                float bce1 = fmaxf(lg, 0.0f) - lg * vt + ln1pe;
                float d1 = sg - vt;
                dsum += d1 * d1 * bce1 - sg * sg * bce0;
            }
        }
    }

    // ---- phase B: localization loss over pred-boost list
    int cnt2 = (int)pcnt2[n];
    float rsum = 0.0f, csum = 0.0f;
    for (int t = tid; t < cnt2; t += 256) {
        u32 p = plistP2[n * 256 + t];
        u64 bk = plistE2[n * 256 + t];
        u64 k = bkeyP[(size_t)n * P + p];
        if (k == bk) {
            float pt = keyval(k);
            float r = pt - 3.0f;
            if (r > 0.0f) {
                int best = (int)(~(u32)(k & 0xFFFFFFFFULL)) & 15;
                const float Bc   = (float)19.085536923187668;
                const float beta = 0.11f;
                float4 pr = *(const float4*)(priors + (size_t)p * 4);
                float tx1 = strt[best * 4],     ty1 = strt[best * 4 + 1];
                float tx2 = strt[best * 4 + 2], ty2 = strt[best * 4 + 3];
                float gcx = ((tx1 + tx2) * 0.5f - pr.x) / (0.1f * pr.z);
                float gcy = ((ty1 + ty2) * 0.5f - pr.y) / (0.1f * pr.w);
                float gw  = flog2((tx2 - tx1) / pr.z) * LN2 / 0.2f;
                float gh  = flog2((ty2 - ty1) / pr.w) * LN2 / 0.2f;
                float4 l  = *(const float4*)(loc + ((size_t)n * P + p) * 4);
                float tgt[4] = {gcx, gcy, gw, gh};
                float lvv[4] = {l.x, l.y, l.z, l.w};
                float s = 0.0f;
                #pragma unroll
                for (int j = 0; j < 4; j++) {
                    float diff = fabsf(lvv[j] - tgt[j]);
                    float bl;
                    if (diff < beta) {
                        bl = 0.5f / Bc * (Bc * diff + 1.0f) *
                             (flog2(1.0f + Bc * diff / beta) * LN2) - 0.5f * diff;
                    } else {
                        bl = 1.5f * diff + 1.5f / Bc - 0.5f * beta;
                    }
                    s += bl;
                }
                rsum += r;
                csum += r * s;
            }
        }
    }

    // ---- combined reduction
    double dd = (double)dsum, dl = (double)csum, dr = (double)rsum;
    long long pp = mypos;
    #pragma unroll
    for (int s = 32; s > 0; s >>= 1) {
        dd += __shfl_down(dd, s, 64);
        dl += __shfl_down(dl, s, 64);
        dr += __shfl_down(dr, s, 64);
        pp += __shfl_down(pp, s, 64);
    }
    __shared__ double wd[4], wl[4], wr[4];
    __shared__ long long wp[4];
    int wv = tid >> 6;
    if ((tid & 63) == 0) { wd[wv] = dd; wl[wv] = dl; wr[wv] = dr; wp[wv] = pp; }
    __syncthreads();
    if (tid == 0) {
        partCC[n] = wd[0] + wd[1] + wd[2] + wd[3];
        partL[n]  = wl[0] + wl[1] + wl[2] + wl[3];
        partR[n]  = wr[0] + wr[1] + wr[2] + wr[3];
        posCnt[n] = (u32)(wp[0] + wp[1] + wp[2] + wp[3]);
    }
}

// ---------- K4: final reduction ----------
__global__ __launch_bounds__(256) void k_fin(
        const double* __restrict__ partC, int nC, const double* __restrict__ partCC,
        const double* __restrict__ partL, const double* __restrict__ partR,
        const u32* __restrict__ posCnt, int N, float* __restrict__ out) {
    int tid = threadIdx.x;
    double sC = 0, sL = 0, sR = 0;
    long long pos = 0;
    for (int i = tid; i < nC; i += 256) sC += partC[i];
    for (int i = tid; i < N; i += 256) {
        sC += partCC[i]; sL += partL[i]; sR += partR[i];
        pos += (long long)posCnt[i];
    }
    #pragma unroll
    for (int s = 32; s > 0; s >>= 1) {
        sC += __shfl_down(sC, s, 64);
        sL += __shfl_down(sL, s, 64);
        sR += __shfl_down(sR, s, 64);
        pos += __shfl_down(pos, s, 64);
    }
    __shared__ double aC[4], aL[4], aR[4];
    __shared__ long long aP[4];
    int wv = tid >> 6;
    if ((tid & 63) == 0) { aC[wv] = sC; aL[wv] = sL; aR[wv] = sR; aP[wv] = pos; }
    __syncthreads();
    if (tid == 0) {
        double tC = aC[0] + aC[1] + aC[2] + aC[3];
        double tL = aL[0] + aL[1] + aL[2] + aL[3];
        double tR = aR[0] + aR[1] + aR[2] + aR[3];
        long long tP = aP[0] + aP[1] + aP[2] + aP[3];
        double npos = tP > 0 ? (double)tP : 1.0;
        out[0] = (float)(tL / (4.0 * tR));
        out[1] = (float)(tC / npos);
    }
}

extern "C" void kernel_launch(void* const* d_in, const int* in_sizes, int n_in,
                              void* d_out, int out_size, void* d_ws, size_t ws_size,
                              hipStream_t stream) {
    const float* loc    = (const float*)d_in[0];
    const float* conf   = (const float*)d_in[1];
    const float* priors = (const float*)d_in[2];
    const float* truths = (const float*)d_in[3];
    const int*   labels = (const int*)d_in[4];

    int P = in_sizes[2] / 4;                 // 18000
    int N = in_sizes[0] / (P * 4);           // 32
    int NBLK = (P + 63) / 64;                // 282
    int CH   = (P + NCH - 1) / NCH;          // 2250
    int ROWS = N * 16;                       // 512
    int nC = NBLK * N;                       // 9024
    // C == 80, O == 16 assumed by kernel tiling

    char* cur = (char*)d_ws;
    auto alloc = [&](size_t bytes) { char* r = cur; cur += (bytes + 255) & ~(size_t)255; return r; };
    u32* pcnt      = (u32*)alloc((size_t)N * 4);
    u32* pcnt2     = (u32*)alloc((size_t)N * 4);
    u32* posCnt    = (u32*)alloc((size_t)N * 4);
    double* partCC = (double*)alloc((size_t)N * 8);
    u32* plistP    = (u32*)alloc((size_t)N * 256 * 4);
    u64* plistE    = (u64*)alloc((size_t)N * 256 * 8);
    u32* plistP2   = (u32*)alloc((size_t)N * 256 * 4);
    u64* plistE2   = (u64*)alloc((size_t)N * 256 * 8);
    double* partC  = (double*)alloc((size_t)nC * 8);
    double* partL  = (double*)alloc((size_t)N * 8);
    double* partR  = (double*)alloc((size_t)N * 8);
    u64* cand      = (u64*)alloc((size_t)2 * ROWS * NCH * 15 * 8);
    u64* basekeyR  = (u64*)alloc((size_t)N * P * 8);
    u64* basekeyP  = (u64*)alloc((size_t)N * P * 8);
    float* out = (float*)d_out;

    dim3 blk(256);
    dim3 gridB(NBLK, N);
    dim3 gridT(NCH, ROWS, 2);
    dim3 gridM(ROWS, 2);

    k_main<<<gridB, blk, 0, stream>>>(loc, conf, priors, truths, labels,
                                      basekeyR, basekeyP, partC, pcnt, pcnt2, P);
    k_tpart<<<gridT, 64, 0, stream>>>(basekeyR, basekeyP, cand, P, CH, ROWS);
    k_tmerge<<<gridM, 64, 0, stream>>>(cand, basekeyR, basekeyP,
                                       plistP, plistE, pcnt,
                                       plistP2, plistE2, pcnt2, P, ROWS);
    k_tail<<<N, blk, 0, stream>>>(conf, loc, priors, truths, labels,
                                  basekeyR, basekeyP,
                                  plistP, plistE, pcnt,
                                  plistP2, plistE2, pcnt2,
                                  partCC, posCnt, partL, partR, P);
    k_fin<<<1, blk, 0, stream>>>(partC, nC, partCC, partL, partR, posCnt, N, out);
}

// Round 15
// 125.858 us; speedup vs baseline: 1.9671x; 1.3835x over previous
//
#include <hip/hip_runtime.h>
#include <hip/hip_bf16.h>

typedef unsigned long long u64;
typedef unsigned int u32;

#define LOG2E 1.44269504088896340736f
#define LN2   0.69314718055994530942f
#define CAP   768

// ---------- fast math ----------
__device__ __forceinline__ float fexp2(float x) { return __builtin_amdgcn_exp2f(x); }
__device__ __forceinline__ float flog2(float x) { return __builtin_amdgcn_logf(x); }
__device__ __forceinline__ float frcp(float x)  { return __builtin_amdgcn_rcpf(x); }
__device__ __forceinline__ float keyval(u64 k) { return __uint_as_float((u32)(k >> 32)); }

__device__ __forceinline__ float iou_xyxy(float ax1, float ay1, float ax2, float ay2,
                                          float bx1, float by1, float bx2, float by2) {
    float ltx = fmaxf(ax1, bx1), lty = fmaxf(ay1, by1);
    float rbx = fminf(ax2, bx2), rby = fminf(ay2, by2);
    float w = fmaxf(rbx - ltx, 0.0f), h = fmaxf(rby - lty, 0.0f);
    float inter = w * h;
    float areaA = (ax2 - ax1) * (ay2 - ay1);
    float areaB = (bx2 - bx1) * (by2 - by1);
    return inter / (areaA + areaB - inter);
}

// ---------- K1: fused main pass (reg path + gfocal stream + pred path) ----------
__global__ __launch_bounds__(256) void k_main(
        const float* __restrict__ loc, const float* __restrict__ conf,
        const float* __restrict__ priors, const float* __restrict__ truths,
        const int* __restrict__ labels,
        u64* __restrict__ basekeyR, u64* __restrict__ basekeyP,
        double* __restrict__ partC, u32* __restrict__ pcnt, u32* __restrict__ pcnt2,
        int P) {
    int n = blockIdx.y, p0 = blockIdx.x * 64, tid = threadIdx.x;
    int r = tid >> 2, sub = tid & 3, p = p0 + r;
    bool act = p < P;

    if (blockIdx.x == 0 && tid == 0) { pcnt[n] = 0u; pcnt2[n] = 0u; }

    float4 L0, L1, L2, L3, L4, prv, lc;
    L0 = L1 = L2 = L3 = L4 = prv = lc = make_float4(0.f, 0.f, 0.f, 0.f);
    if (act) {
        const float* rowp = conf + ((size_t)n * P + p) * 80 + sub * 4;
        L0 = *(const float4*)(rowp);
        L1 = *(const float4*)(rowp + 16);
        L2 = *(const float4*)(rowp + 32);
        L3 = *(const float4*)(rowp + 48);
        L4 = *(const float4*)(rowp + 64);
        prv = *(const float4*)(priors + (size_t)p * 4);
        lc  = *(const float4*)(loc + ((size_t)n * P + p) * 4);
    }

    __shared__ float strt[64];
    __shared__ int   lab[16];
    __shared__ u32   smask[80];
    __shared__ float sglab[64][17];
    if (tid < 64) strt[tid] = truths[n * 64 + tid];
    if (tid < 80) smask[tid] = 0u;
    __syncthreads();
    if (tid < 16) {
        int lb = labels[n * 16 + tid];
        lab[tid] = lb;
        atomicOr(&smask[lb], 1u << tid);
    }
    __syncthreads();

    u32 mybits = 0;
    #pragma unroll
    for (int k = 0; k < 5; k++) {
        #pragma unroll
        for (int j = 0; j < 4; j++) {
            if (smask[k * 16 + sub * 4 + j]) mybits |= 1u << (k * 4 + j);
        }
    }

    // ---- reg path
    {
        float vv[4] = {0, 0, 0, 0};
        float vmax = 0.0f;
        if (act) {
            float cx = prv.x + lc.x * 0.1f * prv.z;
            float cy = prv.y + lc.y * 0.1f * prv.w;
            float w  = prv.z * fexp2(lc.z * 0.2f * LOG2E);
            float h  = prv.w * fexp2(lc.w * 0.2f * LOG2E);
            float bx1 = cx - w * 0.5f, by1 = cy - h * 0.5f;
            float bx2 = cx + w * 0.5f, by2 = cy + h * 0.5f;
            #pragma unroll
            for (int jj = 0; jj < 4; jj++) {
                int o = sub * 4 + jj;
                float v = iou_xyxy(strt[o * 4], strt[o * 4 + 1], strt[o * 4 + 2],
                                   strt[o * 4 + 3], bx1, by1, bx2, by2);
                vv[jj] = v;
                vmax = fmaxf(vmax, v);
            }
        }
        vmax = fmaxf(vmax, __shfl_xor(vmax, 1, 64));
        vmax = fmaxf(vmax, __shfl_xor(vmax, 2, 64));
        u32 bits = 0;
        #pragma unroll
        for (int jj = 0; jj < 4; jj++) {
            if (act && vv[jj] == vmax) bits |= 1u << (sub * 4 + jj);
        }
        bits |= __shfl_xor(bits, 1, 64);
        bits |= __shfl_xor(bits, 2, 64);
        if (act && sub == 0) {
            basekeyR[(size_t)n * P + p] = ((u64)__float_as_uint(vmax) << 32) | bits;
        }
    }

    // ---- gfocal stream, t = 0 everywhere
    float lsum = 0.0f;
    if (act) {
        float lv[20] = {L0.x, L0.y, L0.z, L0.w, L1.x, L1.y, L1.z, L1.w,
                        L2.x, L2.y, L2.z, L2.w, L3.x, L3.y, L3.z, L3.w,
                        L4.x, L4.y, L4.z, L4.w};
        #pragma unroll
        for (int k = 0; k < 5; k++) {
            #pragma unroll
            for (int j = 0; j < 4; j++) {
                float lg = lv[k * 4 + j];
                float e  = fexp2(-fabsf(lg) * LOG2E);
                float ln1pe = flog2(1.0f + e) * LN2;
                float rc = frcp(1.0f + e);
                float sg = (lg >= 0.0f) ? rc : e * rc;
                lsum += sg * sg * (fmaxf(lg, 0.0f) + ln1pe);
                if (mybits & (1u << (k * 4 + j))) {
                    u32 m16 = smask[k * 16 + sub * 4 + j];
                    while (m16) {
                        int o = __ffs(m16) - 1;
                        sglab[r][o] = sg;
                        m16 &= m16 - 1;
                    }
                }
            }
        }
    }
    __syncthreads();

    // ---- pred path
    {
        float pv[4] = {0, 0, 0, 0};
        float pmax = 0.0f;
        if (act) {
            float px1 = prv.x - prv.z * 0.5f, py1 = prv.y - prv.w * 0.5f;
            float px2 = prv.x + prv.z * 0.5f, py2 = prv.y + prv.w * 0.5f;
            #pragma unroll
            for (int jj = 0; jj < 4; jj++) {
                int o = sub * 4 + jj;
                float ov = iou_xyxy(strt[o * 4], strt[o * 4 + 1], strt[o * 4 + 2],
                                    strt[o * 4 + 3], px1, py1, px2, py2);
                float pd = 0.0f;
                if (ov > 0.0f) {
                    float pc = sglab[r][o];
                    pd = fexp2((2.0f - pc) * 0.5f * flog2(ov));
                }
                pv[jj] = pd;
                pmax = fmaxf(pmax, pd);
            }
        }
        pmax = fmaxf(pmax, __shfl_xor(pmax, 1, 64));
        pmax = fmaxf(pmax, __shfl_xor(pmax, 2, 64));
        u32 bits = 0;
        #pragma unroll
        for (int jj = 0; jj < 4; jj++) {
            if (act && pv[jj] == pmax) bits |= 1u << (sub * 4 + jj);
        }
        bits |= __shfl_xor(bits, 1, 64);
        bits |= __shfl_xor(bits, 2, 64);
        if (act && sub == 0) {
            basekeyP[(size_t)n * P + p] = ((u64)__float_as_uint(pmax) << 32) | bits;
        }
    }

    #pragma unroll
    for (int s = 32; s > 0; s >>= 1) lsum += __shfl_down(lsum, s, 64);
    __shared__ float wsum[4];
    if ((tid & 63) == 0) wsum[tid >> 6] = lsum;
    __syncthreads();
    if (tid == 0) {
        partC[(size_t)blockIdx.y * gridDim.x + blockIdx.x] =
            (double)wsum[0] + (double)wsum[1] + (double)wsum[2] + (double)wsum[3];
    }
}

// ---------- K2: per-(row,z) exact top-15 via histogram radix-select ----------
// No cross-lane merges: histogram (2048 bins over key high bits) -> suffix scan
// -> collect candidates in bins >= B -> rank-by-counting (keys unique).
__global__ __launch_bounds__(256) void k_sel(
        const u64* __restrict__ basekeyR, const u64* __restrict__ basekeyP,
        u64* __restrict__ selk, int P, int ROWS) {
    int row = blockIdx.x, z = blockIdx.y, tid = threadIdx.x;
    int n = row >> 4, o = row & 15;
    const u64* base = (z ? basekeyP : basekeyR) + (size_t)n * P;

    __shared__ u32 hist[2048];
    __shared__ u32 tsum[256];
    __shared__ int sB;
    __shared__ u32 sSB;
    __shared__ u32 sT;
    __shared__ u64 cand[CAP];
    __shared__ u32 scnt;
    __shared__ u64 sel[15];

    if (tid == 0) scnt = 0u;
    if (tid < 15) sel[tid] = 0ULL;

    u64 pmask = 0, pval = 0;
    int shift = 53;
    int k = 0;
    int need = 15;
    bool done = false;

    for (int lvl = 0; lvl < 3 && !done; lvl++) {
        #pragma unroll
        for (int i = 0; i < 8; i++) hist[tid + i * 256] = 0u;
        __syncthreads();
        for (int i = tid * 2; i < P; i += 512) {
            ulonglong2 v = *(const ulonglong2*)(base + i);
            u64 b0 = v.x, b1 = v.y;
            if ((u32)(b0 >> 32) != 0u && ((b0 >> o) & 1) && (b0 & pmask) == pval)
                atomicAdd(&hist[(u32)(b0 >> shift) & 2047u], 1u);
            if ((u32)(b1 >> 32) != 0u && ((b1 >> o) & 1) && (b1 & pmask) == pval)
                atomicAdd(&hist[(u32)(b1 >> shift) & 2047u], 1u);
        }
        __syncthreads();
        // per-thread local suffix over its 8 bins
        u32 l_[8], ls[8];
        #pragma unroll
        for (int i = 0; i < 8; i++) l_[i] = hist[tid * 8 + i];
        ls[7] = l_[7];
        #pragma unroll
        for (int i = 6; i >= 0; i--) ls[i] = ls[i + 1] + l_[i];
        tsum[tid] = ls[0];
        __syncthreads();
        // Hillis-Steele inclusive suffix scan over thread totals
        for (int d = 1; d < 256; d <<= 1) {
            u32 v = (tid + d < 256) ? tsum[tid + d] : 0u;
            __syncthreads();
            tsum[tid] += v;
            __syncthreads();
        }
        if (lvl == 0) {
            if (tid == 0) sT = tsum[0];
            __syncthreads();
            u32 T = sT;
            if (T == 0u) { k = 0; break; }         // empty row
            k = (T < 15u) ? (int)T : 15;
            need = k;
        }
        u32 off = (tid < 255) ? tsum[tid + 1] : 0u;
        int myB = -1;
        #pragma unroll
        for (int i = 0; i < 8; i++) {
            u32 S = ls[i] + off;
            if ((int)S >= need) { int b = tid * 8 + i; if (b > myB) myB = b; }
        }
        if (tid == 0) sB = -1;
        __syncthreads();
        if (myB >= 0) atomicMax(&sB, myB);
        __syncthreads();
        int B = sB;
        if (B >= 0 && (B >> 3) == tid) sSB = ls[B & 7] + off;
        __syncthreads();
        u32 SB = sSB;
        bool last = (lvl == 2);
        bool fits = ((scnt + SB) <= (u32)CAP) || last;
        for (int i = tid * 2; i < P; i += 512) {
            ulonglong2 v = *(const ulonglong2*)(base + i);
            #pragma unroll
            for (int j = 0; j < 2; j++) {
                u64 b = (j == 0) ? v.x : v.y;
                int pp = i + j;
                if ((u32)(b >> 32) != 0u && ((b >> o) & 1) && (b & pmask) == pval) {
                    int bin = (int)((u32)(b >> shift) & 2047u);
                    bool take = fits ? (bin >= B) : (bin > B);
                    if (take) {
                        u32 idx = atomicAdd(&scnt, 1u);
                        if (idx < (u32)CAP)
                            cand[idx] = (b & 0xFFFFFFFF00000000ULL) | (u32)(~(u32)pp);
                    }
                }
            }
        }
        __syncthreads();
        if (fits) {
            done = true;
        } else {
            need = k - (int)scnt;
            pmask |= (u64)2047u << shift;
            pval |= ((u64)(u32)B) << shift;
            shift -= 11;
            __syncthreads();
        }
    }

    __syncthreads();
    if (k > 0) {
        u32 cnt = scnt; if (cnt > (u32)CAP) cnt = (u32)CAP;
        for (u32 i = tid; i < cnt; i += 256) {
            u64 key = cand[i];
            int rank = 0;
            for (u32 c = 0; c < cnt; c++) rank += (cand[c] > key) ? 1 : 0;
            if (rank < k) sel[rank] = key;
        }
    }
    __syncthreads();
    if (tid < 15) selk[((size_t)z * ROWS + row) * 16 + tid] = sel[tid];
}

// ---------- K3: apply boosts + record lists (separate kernel: no scan race) ---------
__global__ __launch_bounds__(64) void k_boost(
        const u64* __restrict__ selk,
        u64* __restrict__ basekeyR, u64* __restrict__ basekeyP,
        u32* __restrict__ plistP, u64* __restrict__ plistE, u32* __restrict__ pcnt,
        u32* __restrict__ plistP2, u64* __restrict__ plistE2, u32* __restrict__ pcnt2,
        int P, int ROWS) {
    int row = blockIdx.x, z = blockIdx.y, tid = threadIdx.x;
    int n = row >> 4, o = row & 15;
    u64* bkey = z ? basekeyP : basekeyR;
    u32* lp = z ? plistP2 : plistP;
    u64* le = z ? plistE2 : plistE;
    u32* lc = z ? pcnt2 : pcnt;
    const u64* src = selk + ((size_t)z * ROWS + row) * 16;

    __shared__ int sh_num;
    if (tid == 0) {
        float s = 0.0f; int pc = 0;
        #pragma unroll
        for (int j = 0; j < 15; j++) {
            float v = keyval(src[j]);
            s += v;
            if (v > 0.0f) pc++;
        }
        int np = (int)s; if (np < 1) np = 1;
        if (pc == 0) {
            // empty row: top_k -> indices 0..14, num_pos=1 -> boost entry p=0
            u64 bk = ((u64)__float_as_uint(3.0f) << 32) | (u32)(~(u32)o);
            atomicMax(&bkey[(size_t)n * P + 0], bk);
            u32 idx = atomicAdd(&lc[n], 1u);
            lp[n * 256 + idx] = 0u;
            le[n * 256 + idx] = bk;
            sh_num = 0;
        } else {
            sh_num = np;
        }
    }
    __syncthreads();
    if (tid < 15 && tid < sh_num) {
        u64 kx = src[tid];
        float v = keyval(kx);
        if (v > 0.0f) {
            u32 pidx = ~(u32)(kx & 0xFFFFFFFFULL);
            u64 bk = ((u64)__float_as_uint(v + 3.0f) << 32) | (u32)(~(u32)o);
            atomicMax(&bkey[(size_t)n * P + pidx], bk);
            u32 idx = atomicAdd(&lc[n], 1u);
            lp[n * 256 + idx] = pidx;
            le[n * 256 + idx] = bk;
        }
    }
}

// ---------- K4: fused tail — gfocal corrections + posCount + localization loss ------
__global__ __launch_bounds__(256) void k_tail(
        const float* __restrict__ conf, const float* __restrict__ loc,
        const float* __restrict__ priors, const float* __restrict__ truths,
        const int* __restrict__ labels,
        const u64* __restrict__ bkeyR, const u64* __restrict__ bkeyP,
        const u32* __restrict__ plistP, const u64* __restrict__ plistE,
        const u32* __restrict__ pcnt,
        const u32* __restrict__ plistP2, const u64* __restrict__ plistE2,
        const u32* __restrict__ pcnt2,
        double* __restrict__ partCC, u32* __restrict__ posCnt,
        double* __restrict__ partL, double* __restrict__ partR, int P) {
    int n = blockIdx.x, tid = threadIdx.x;
    __shared__ int lab[16];
    __shared__ float strt[64];
    if (tid < 16) lab[tid] = labels[n * 16 + tid];
    if (tid < 64) strt[tid] = truths[n * 64 + tid];
    __syncthreads();

    int cnt = (int)pcnt[n];
    float dsum = 0.0f;
    int mypos = 0;
    for (int t = tid; t < cnt; t += 256) {
        u32 p = plistP[n * 256 + t];
        u64 bk = plistE[n * 256 + t];
        u64 kx = bkeyR[(size_t)n * P + p];
        if (kx == bk) {
            float v3 = keyval(kx);
            float vt = v3 - 3.0f;
            if (vt > 0.0f) {
                mypos++;
                int o = (int)(~(u32)(kx & 0xFFFFFFFFULL)) & 15;
                int tcls = lab[o];
                float lg = conf[((size_t)n * P + p) * 80 + tcls];
                float e  = fexp2(-fabsf(lg) * LOG2E);
                float ln1pe = flog2(1.0f + e) * LN2;
                float rc = frcp(1.0f + e);
                float sg = (lg >= 0.0f) ? rc : e * rc;
                float bce0 = fmaxf(lg, 0.0f) + ln1pe;
                float bce1 = fmaxf(lg, 0.0f) - lg * vt + ln1pe;
                float d1 = sg - vt;
                dsum += d1 * d1 * bce1 - sg * sg * bce0;
            }
        }
    }

    int cnt2 = (int)pcnt2[n];
    float rsum = 0.0f, csum = 0.0f;
    for (int t = tid; t < cnt2; t += 256) {
        u32 p = plistP2[n * 256 + t];
        u64 bk = plistE2[n * 256 + t];
        u64 kx = bkeyP[(size_t)n * P + p];
        if (kx == bk) {
            float pt = keyval(kx);
            float r = pt - 3.0f;
            if (r > 0.0f) {
                int best = (int)(~(u32)(kx & 0xFFFFFFFFULL)) & 15;
                const float Bc   = (float)19.085536923187668;
                const float beta = 0.11f;
                float4 pr = *(const float4*)(priors + (size_t)p * 4);
                float tx1 = strt[best * 4],     ty1 = strt[best * 4 + 1];
                float tx2 = strt[best * 4 + 2], ty2 = strt[best * 4 + 3];
                float gcx = ((tx1 + tx2) * 0.5f - pr.x) / (0.1f * pr.z);
                float gcy = ((ty1 + ty2) * 0.5f - pr.y) / (0.1f * pr.w);
                float gw  = flog2((tx2 - tx1) / pr.z) * LN2 / 0.2f;
                float gh  = flog2((ty2 - ty1) / pr.w) * LN2 / 0.2f;
                float4 l  = *(const float4*)(loc + ((size_t)n * P + p) * 4);
                float tgt[4] = {gcx, gcy, gw, gh};
                float lvv[4] = {l.x, l.y, l.z, l.w};
                float s = 0.0f;
                #pragma unroll
                for (int j = 0; j < 4; j++) {
                    float diff = fabsf(lvv[j] - tgt[j]);
                    float bl;
                    if (diff < beta) {
                        bl = 0.5f / Bc * (Bc * diff + 1.0f) *
                             (flog2(1.0f + Bc * diff / beta) * LN2) - 0.5f * diff;
                    } else {
                        bl = 1.5f * diff + 1.5f / Bc - 0.5f * beta;
                    }
                    s += bl;
                }
                rsum += r;
                csum += r * s;
            }
        }
    }

    double dd = (double)dsum, dl = (double)csum, dr = (double)rsum;
    long long pp = mypos;
    #pragma unroll
    for (int s = 32; s > 0; s >>= 1) {
        dd += __shfl_down(dd, s, 64);
        dl += __shfl_down(dl, s, 64);
        dr += __shfl_down(dr, s, 64);
        pp += __shfl_down(pp, s, 64);
    }
    __shared__ double wd[4], wl[4], wr[4];
    __shared__ long long wp[4];
    int wv = tid >> 6;
    if ((tid & 63) == 0) { wd[wv] = dd; wl[wv] = dl; wr[wv] = dr; wp[wv] = pp; }
    __syncthreads();
    if (tid == 0) {
        partCC[n] = wd[0] + wd[1] + wd[2] + wd[3];
        partL[n]  = wl[0] + wl[1] + wl[2] + wl[3];
        partR[n]  = wr[0] + wr[1] + wr[2] + wr[3];
        posCnt[n] = (u32)(wp[0] + wp[1] + wp[2] + wp[3]);
    }
}

// ---------- K5: final reduction ----------
__global__ __launch_bounds__(256) void k_fin(
        const double* __restrict__ partC, int nC, const double* __restrict__ partCC,
        const double* __restrict__ partL, const double* __restrict__ partR,
        const u32* __restrict__ posCnt, int N, float* __restrict__ out) {
    int tid = threadIdx.x;
    double sC = 0, sL = 0, sR = 0;
    long long pos = 0;
    for (int i = tid; i < nC; i += 256) sC += partC[i];
    for (int i = tid; i < N; i += 256) {
        sC += partCC[i]; sL += partL[i]; sR += partR[i];
        pos += (long long)posCnt[i];
    }
    #pragma unroll
    for (int s = 32; s > 0; s >>= 1) {
        sC += __shfl_down(sC, s, 64);
        sL += __shfl_down(sL, s, 64);
        sR += __shfl_down(sR, s, 64);
        pos += __shfl_down(pos, s, 64);
    }
    __shared__ double aC[4], aL[4], aR[4];
    __shared__ long long aP[4];
    int wv = tid >> 6;
    if ((tid & 63) == 0) { aC[wv] = sC; aL[wv] = sL; aR[wv] = sR; aP[wv] = pos; }
    __syncthreads();
    if (tid == 0) {
        double tC = aC[0] + aC[1] + aC[2] + aC[3];
        double tL = aL[0] + aL[1] + aL[2] + aL[3];
        double tR = aR[0] + aR[1] + aR[2] + aR[3];
        long long tP = aP[0] + aP[1] + aP[2] + aP[3];
        double npos = tP > 0 ? (double)tP : 1.0;
        out[0] = (float)(tL / (4.0 * tR));
        out[1] = (float)(tC / npos);
    }
}

extern "C" void kernel_launch(void* const* d_in, const int* in_sizes, int n_in,
                              void* d_out, int out_size, void* d_ws, size_t ws_size,
                              hipStream_t stream) {
    const float* loc    = (const float*)d_in[0];
    const float* conf   = (const float*)d_in[1];
    const float* priors = (const float*)d_in[2];
    const float* truths = (const float*)d_in[3];
    const int*   labels = (const int*)d_in[4];

    int P = in_sizes[2] / 4;                 // 18000
    int N = in_sizes[0] / (P * 4);           // 32
    int NBLK = (P + 63) / 64;                // 282
    int ROWS = N * 16;                       // 512
    int nC = NBLK * N;                       // 9024
    // C == 80, O == 16, P even assumed by kernel tiling

    char* cur = (char*)d_ws;
    auto alloc = [&](size_t bytes) { char* r = cur; cur += (bytes + 255) & ~(size_t)255; return r; };
    u32* pcnt      = (u32*)alloc((size_t)N * 4);
    u32* pcnt2     = (u32*)alloc((size_t)N * 4);
    u32* posCnt    = (u32*)alloc((size_t)N * 4);
    double* partCC = (double*)alloc((size_t)N * 8);
    u32* plistP    = (u32*)alloc((size_t)N * 256 * 4);
    u64* plistE    = (u64*)alloc((size_t)N * 256 * 8);
    u32* plistP2   = (u32*)alloc((size_t)N * 256 * 4);
    u64* plistE2   = (u64*)alloc((size_t)N * 256 * 8);
    double* partC  = (double*)alloc((size_t)nC * 8);
    double* partL  = (double*)alloc((size_t)N * 8);
    double* partR  = (double*)alloc((size_t)N * 8);
    u64* selk      = (u64*)alloc((size_t)2 * ROWS * 16 * 8);
    u64* basekeyR  = (u64*)alloc((size_t)N * P * 8);
    u64* basekeyP  = (u64*)alloc((size_t)N * P * 8);
    float* out = (float*)d_out;

    dim3 blk(256);
    dim3 gridB(NBLK, N);
    dim3 gridS(ROWS, 2);

    k_main<<<gridB, blk, 0, stream>>>(loc, conf, priors, truths, labels,
                                      basekeyR, basekeyP, partC, pcnt, pcnt2, P);
    k_sel<<<gridS, blk, 0, stream>>>(basekeyR, basekeyP, selk, P, ROWS);
    k_boost<<<gridS, 64, 0, stream>>>(selk, basekeyR, basekeyP,
                                      plistP, plistE, pcnt,
                                      plistP2, plistE2, pcnt2, P, ROWS);
    k_tail<<<N, blk, 0, stream>>>(conf, loc, priors, truths, labels,
                                  basekeyR, basekeyP,
                                  plistP, plistE, pcnt,
                                  plistP2, plistE2, pcnt2,
                                  partCC, posCnt, partL, partR, P);
    k_fin<<<1, blk, 0, stream>>>(partC, nC, partCC, partL, partR, posCnt, N, out);
}